// Round 11
// baseline (5163.424 us; speedup 1.0000x reference)
//
#include <hip/hip_runtime.h>
#include <hip/hip_bf16.h>

// TextRNN: embed -> 2-layer LSTM (B=64,T=256,H=1024) -> proj 32000, f32 out.
// R11 = R10 k_mega + FUSED G1 producer role (overlap: gemx ran serially before
// mega while mega's sync-stall floor left CUs idle).
//   grid 512 x 512thr: blocks 0-255 produce G1 chunk-by-chunk (16 t each),
//   agent-release atomicAdd gprog[tc]; blocks 256-511 = R10 mega, gating the
//   G(r+1) prefetch on gprog[(r+1)>>4]==64 + agent-acquire (once / 16 rounds).
// Deadlock-safe by construction: launch_bounds(512,4) caps VGPR at 128 (the
// allocator's observed choice) and LDS=72KB -> 2 blocks/CU -> all 512 blocks
// co-resident regardless of dispatch order; worst case = serial (status quo).

typedef __attribute__((ext_vector_type(8))) short s16x8;
typedef __attribute__((ext_vector_type(4))) float f32x4;
typedef unsigned long long u64;

#define N_CLASS 32000
#define EMB 512
#define HID 1024
#define BATCH 64
#define SEQ 256
#define NG4 4096

#define PIN(v) asm volatile("" : "+v"(v))

static __device__ __forceinline__ short f2bf(float x) {
  __hip_bfloat16 h = __float2bfloat16(x);
  return *reinterpret_cast<short*>(&h);
}
static __device__ __forceinline__ float bf2f(short x) {
  __hip_bfloat16 h = *reinterpret_cast<__hip_bfloat16*>(&x);
  return __bfloat162float(h);
}
static __device__ __forceinline__ float fsigm(float x) {
  return __builtin_amdgcn_rcpf(1.f + __expf(-x));
}
static __device__ __forceinline__ float ftanh(float x) {
  return 2.f * __builtin_amdgcn_rcpf(1.f + __expf(-2.f * x)) - 1.f;
}

// ---- weight conversion to swizzled bf16 B-layout: sw[((k>>3)*4096+n)*8+(k&7)]
__global__ void k_conv_w4(const float* __restrict__ Wg, const float* __restrict__ Wi,
                          const float* __restrict__ Wf, const float* __restrict__ Wo,
                          short* __restrict__ sw, int K) {
  int i = blockIdx.x * 256 + threadIdx.x;
  int k8 = i >> 10, j = i & 1023;
  if (k8 >= (K >> 3)) return;
  const float* W = blockIdx.z == 0 ? Wg : blockIdx.z == 1 ? Wi : blockIdx.z == 2 ? Wf : Wo;
  s16x8 v;
#pragma unroll
  for (int e = 0; e < 8; ++e) v[e] = f2bf(W[(size_t)(k8 * 8 + e) * 1024 + j]);
  *(s16x8*)(sw + ((size_t)k8 * NG4 + blockIdx.z * 1024 + j) * 8) = v;
}

__global__ void k_bcat(const float* __restrict__ b0, const float* __restrict__ b1,
                       const float* __restrict__ b2, const float* __restrict__ b3,
                       float* __restrict__ dst) {
  int i = blockIdx.x * 256 + threadIdx.x;  // 4096
  const float* s = (i >> 10) == 0 ? b0 : (i >> 10) == 1 ? b1 : (i >> 10) == 2 ? b2 : b3;
  dst[i] = s[i & 1023];
}

__global__ void k_f2bf(const float* __restrict__ src, short* __restrict__ dst, int n) {
  int i = blockIdx.x * 256 + threadIdx.x;
  if (i < n) dst[i] = f2bf(src[i]);
}

// ---- embedding gather --------------------------------------------------------
__global__ void k_embed(const int* __restrict__ X, const float* __restrict__ C,
                        short* __restrict__ xs) {
  int r = blockIdx.x;
  int t = r >> 6, b = r & 63;
  int idx = X[b * SEQ + t];
  const float* src = C + (size_t)idx * EMB;
  float2 v = *(const float2*)(src + threadIdx.x * 2);
  short* dst = xs + (size_t)r * EMB + threadIdx.x * 2;
  dst[0] = f2bf(v.x);
  dst[1] = f2bf(v.y);
}

// ---- fused producer(G1) + persistent 2-layer recurrence ----------------------
__global__ __launch_bounds__(512, 4) void k_mega(
    u64* __restrict__ G64, const short* __restrict__ Wh1sw,
    const short* __restrict__ Wx2sw, const short* __restrict__ Wh2sw,
    const float* __restrict__ bc2, u64* __restrict__ h1ex, u64* __restrict__ h2ex,
    const float* __restrict__ c0, const float* __restrict__ c0y,
    u64* __restrict__ hTy, unsigned* __restrict__ flags,
    const short* __restrict__ xs, const short* __restrict__ Wx1sw,
    const float* __restrict__ bc1) {
  __shared__ char smem[73728];  // gemx: 64KB B-panel | mega: 64KB A-tiles + 8KB xch
  const int tid = threadIdx.x;
  const int lane = tid & 63, W = tid >> 6;
  const int l15 = lane & 15, l4 = lane >> 4;
  unsigned* gprog = flags + 12288;  // [16] chunk counters, stride 32 u32

  if ((int)blockIdx.x < 256) {
    // ================= producer role: G1 = xs@Wx1 + b1, chunked =================
    short* lds = (short*)smem;  // B panel: K=512 x 64 cols
    const int n0 = ((int)blockIdx.x & 63) * 64;
    const int mq = (int)blockIdx.x >> 6;  // 0..3 -> chunks [mq*4, mq*4+4)
    for (int cid = tid; cid < 4096; cid += 512) {
      int k8 = cid >> 6, nl = cid & 63;
      *(s16x8*)(lds + (size_t)cid * 8) =
          *(const s16x8*)(Wx1sw + ((size_t)k8 * NG4 + n0 + nl) * 8);
    }
    __syncthreads();
    const int ms = W >> 2, ns = W & 3;
    const int colg = n0 + ns * 16 + l15;
    const float bv = bc1[colg];
    const int q = colg >> 10, nslc = (colg >> 4) & 63;
    for (int tc = mq * 4; tc < mq * 4 + 4; ++tc) {
      for (int mt = 0; mt < 16; ++mt) {
        int m0 = tc * 1024 + mt * 64;
        f32x4 acc0 = (f32x4){0.f, 0.f, 0.f, 0.f};
        f32x4 acc1 = (f32x4){0.f, 0.f, 0.f, 0.f};
        const short* a0p = xs + (size_t)(m0 + ms * 32 + l15) * EMB + l4 * 8;
        const short* a1p = a0p + (size_t)16 * EMB;
#pragma unroll 4
        for (int kc = 0; kc < 16; ++kc) {
          s16x8 av0 = *(const s16x8*)(a0p + kc * 32);
          s16x8 av1 = *(const s16x8*)(a1p + kc * 32);
          s16x8 bvv = *(const s16x8*)(lds + (size_t)((kc * 4 + l4) * 64 + ns * 16 + l15) * 8);
          acc0 = __builtin_amdgcn_mfma_f32_16x16x32_bf16(av0, bvv, acc0, 0, 0, 0);
          acc1 = __builtin_amdgcn_mfma_f32_16x16x32_bf16(av1, bvv, acc1, 0, 0, 0);
        }
        int t = m0 >> 6;
        u64 pk0 = 0, pk1 = 0;
#pragma unroll
        for (int e = 0; e < 4; ++e) {
          pk0 |= (u64)(unsigned short)f2bf(acc0[e] + bv) << (16 * e);
          pk1 |= (u64)(unsigned short)f2bf(acc1[e] + bv) << (16 * e);
        }
        size_t s0 = ((((size_t)t * 4 + ms * 2) * 64 + nslc) * 4 + q) * 64 + l4 * 16 + l15;
        G64[s0] = pk0;
        G64[s0 + 16384] = pk1;  // grp+1
      }
      asm volatile("s_waitcnt vmcnt(0)" ::: "memory");
      __syncthreads();  // all waves' stores for chunk tc drained
      if (tid == 0)
        __hip_atomic_fetch_add(gprog + tc * 32, 1u, __ATOMIC_RELEASE,
                               __HIP_MEMORY_SCOPE_AGENT);
    }
    return;
  }

  // ================= mega role (R10 body) =================
  const int bid2 = (int)blockIdx.x - 256;
  short* a_lds = (short*)smem;                       // 64KB: A1 | A2
  f32x4* xch = (f32x4*)(smem + 65536);               // [8][64]
  const int wv = W & 3, khalf = W >> 2;
  // nsl-colocating XCD remap (R10): all 4 group-copies of a weight slice on
  // one XCD; 8 distinct slices (3.07MB) per L2.
  const int xcd = bid2 & 7;
  const int idx = bid2 >> 3;  // 0..31
  const int group = idx & 3;
  const int nsl = ((idx >> 2) << 3) | xcd;
  const int col = (l15 >> 2) * 1024 + nsl * 16 + wv * 4 + (l15 & 3);

  s16x8 b1r[16], bxr[16], b2r[16];
#pragma unroll
  for (int j = 0; j < 16; ++j) {
    size_t o = ((size_t)((khalf * 16 + j) * 4 + l4) * NG4 + col) * 8;
    b1r[j] = *(const s16x8*)(Wh1sw + o);
    PIN(b1r[j]);
  }
#pragma unroll
  for (int j = 0; j < 16; ++j) {
    size_t o = ((size_t)((khalf * 16 + j) * 4 + l4) * NG4 + col) * 8;
    bxr[j] = *(const s16x8*)(Wx2sw + o);
    PIN(bxr[j]);
  }
#pragma unroll
  for (int j = 0; j < 16; ++j) {
    size_t o = ((size_t)((khalf * 16 + j) * 4 + l4) * NG4 + col) * 8;
    b2r[j] = *(const s16x8*)(Wh2sw + o);
    PIN(b2r[j]);
  }
  const float bias2 = bc2[col];
  float cv[4];  // c1 on waves 0-3, c2 on waves 4-7
#pragma unroll
  for (int e = 0; e < 4; ++e) {
    int gi = (group * 16 + l4 * 4 + e) * HID + nsl * 16 + wv * 4 + (l15 & 3);
    cv[e] = (W < 4 ? c0 : c0y)[gi];
  }
  unsigned* arr = flags;  // [4][64] slots, stride 32 u32 (128B)
  const int srow = tid >> 5, sc5 = tid & 31;
  const int exrow = (group * 16 + srow) * 256;
  const size_t gbase =
      (((size_t)group * 64 + nsl) * 4 + (l15 >> 2)) * 64 + l4 * 16 + wv * 4 + (l15 & 3);
  const int gsrc = l4 * 16 + (l15 & 3);
  const int psrc = ((l15 >> 2) << 4) + ((l15 & 3) << 2);
  const int swzm = (l15 & 7) << 4;
  const int abase = l15 * 2048 + khalf * 1024 + l4 * 16;

  u64 gcur = 0, gnext = 0;
  int readyc = -1;
  if (W < 4) {  // gate chunk 0, then load G(0)
    while (__hip_atomic_load(gprog, __ATOMIC_RELAXED, __HIP_MEMORY_SCOPE_AGENT) < 64u)
      __builtin_amdgcn_s_sleep(8);
    __builtin_amdgcn_fence(__ATOMIC_ACQUIRE, "agent");
    readyc = 0;
    gcur = G64[gbase];
  }

  for (int r = 0; r <= 256; ++r) {
    // gated prefetch of G(r+1): chunk gate once per 16 rounds
    if (W < 4 && r + 1 < 256) {
      int nc = (r + 1) >> 4;
      if (nc > readyc) {
        while (__hip_atomic_load(gprog + nc * 32, __ATOMIC_RELAXED,
                                 __HIP_MEMORY_SCOPE_AGENT) < 64u)
          __builtin_amdgcn_s_sleep(8);
        __builtin_amdgcn_fence(__ATOMIC_ACQUIRE, "agent");
        readyc = nc;
      }
      gnext = G64[gbase + (size_t)(r + 1) * 65536];
    }
    if (r > 0) {
      if (tid < 64) {
        unsigned* p = arr + ((group << 6) + tid) * 32;
        while (__hip_atomic_load(p, __ATOMIC_RELAXED, __HIP_MEMORY_SCOPE_AGENT) <
               (unsigned)r)
          __builtin_amdgcn_s_sleep(1);
      }
      __syncthreads();
      asm volatile("" ::: "memory");
    }
    {  // stage A1 = h1(r-1), A2 = h2(r-2) from ring slot (r+1)&1
      const int slot = (r + 1) & 1;
      const u64* s1 = h1ex + slot * 16384 + exrow;
      const u64* s2 = h2ex + slot * 16384 + exrow;
#pragma unroll
      for (int i = 0; i < 8; ++i) {
        int chunk = sc5 + (i << 5);
        u64 v1 = __hip_atomic_load(s1 + chunk, __ATOMIC_RELAXED, __HIP_MEMORY_SCOPE_AGENT);
        u64 v2 = __hip_atomic_load(s2 + chunk, __ATOMIC_RELAXED, __HIP_MEMORY_SCOPE_AGENT);
        int bo = (srow * 2048 + chunk * 8) ^ ((srow & 7) << 4);
        *(u64*)((char*)a_lds + bo) = v1;
        *(u64*)((char*)a_lds + 32768 + bo) = v2;
      }
    }
    __syncthreads();

    // ---- MFMA: 3 chains (L1, L2-x, L2-h), 16 deep each (this wave's K half)
    f32x4 p1, p2a, p2b;
    if (W < 4) {
#pragma unroll
      for (int e = 0; e < 4; ++e)
        p1[e] = __uint_as_float((unsigned)((gcur >> (16 * e)) & 0xffffu) << 16);
      p2a = (f32x4){0.f, 0.f, 0.f, 0.f};
    } else {
      p1 = (f32x4){0.f, 0.f, 0.f, 0.f};
      p2a = (f32x4){bias2, bias2, bias2, bias2};
    }
    p2b = (f32x4){0.f, 0.f, 0.f, 0.f};
#pragma unroll
    for (int j = 0; j < 16; ++j) {
      int o = (abase + j * 64) ^ swzm;
      s16x8 a1 = *(const s16x8*)((const char*)a_lds + o);
      s16x8 a2 = *(const s16x8*)((const char*)a_lds + 32768 + o);
      p1 = __builtin_amdgcn_mfma_f32_16x16x32_bf16(a1, b1r[j], p1, 0, 0, 0);
      p2a = __builtin_amdgcn_mfma_f32_16x16x32_bf16(a1, bxr[j], p2a, 0, 0, 0);
      p2b = __builtin_amdgcn_mfma_f32_16x16x32_bf16(a2, b2r[j], p2b, 0, 0, 0);
    }
    f32x4 p2 = p2a + p2b;
    // ---- cross-wave-pair partial exchange
    if (W < 4) {
      if (r >= 1) xch[W * 64 + lane] = p2;
    } else {
      if (r < 256) xch[W * 64 + lane] = p1;
    }
    __syncthreads();

    if (W < 4) {
      if (r < 256) {  // layer-1 activation, h1(r)
        f32x4 po = xch[(W + 4) * 64 + lane];
        f32x4 acc = p1 + po;
        float hh0, hh1, hh2, hh3;
#pragma unroll
        for (int e = 0; e < 4; ++e) {
          float xg = __shfl(acc[e], gsrc + 0);
          float xi = __shfl(acc[e], gsrc + 4);
          float xf = __shfl(acc[e], gsrc + 8);
          float xo = __shfl(acc[e], gsrc + 12);
          float cn = cv[e] * fsigm(xf) + ftanh(xg) * fsigm(xi);
          cv[e] = cn;
          float hv = ftanh(cn) * fsigm(xo);
          if (e == 0) hh0 = hv;
          else if (e == 1) hh1 = hv;
          else if (e == 2) hh2 = hv;
          else hh3 = hv;
        }
        int rr = l15 >> 2;
        float hexp = rr == 0 ? hh0 : rr == 1 ? hh1 : rr == 2 ? hh2 : hh3;
        float p0 = __shfl(hexp, psrc + 0);
        float p1s = __shfl(hexp, psrc + 1);
        float p2s = __shfl(hexp, psrc + 2);
        float p3s = __shfl(hexp, psrc + 3);
        if (lane < 16) {
          u64 pk = (u64)(unsigned short)f2bf(p0) | ((u64)(unsigned short)f2bf(p1s) << 16) |
                   ((u64)(unsigned short)f2bf(p2s) << 32) |
                   ((u64)(unsigned short)f2bf(p3s) << 48);
          __hip_atomic_store(
              h1ex + (r & 1) * 16384 + (group * 16 + lane) * 256 + nsl * 4 + wv, pk,
              __ATOMIC_RELAXED, __HIP_MEMORY_SCOPE_AGENT);
        }
      }
    } else {
      if (r >= 1) {  // layer-2 activation, h2(r-1)
        f32x4 po = xch[(W - 4) * 64 + lane];
        f32x4 acc = p2 + po;
        float hh0, hh1, hh2, hh3;
#pragma unroll
        for (int e = 0; e < 4; ++e) {
          float xg = __shfl(acc[e], gsrc + 0);
          float xi = __shfl(acc[e], gsrc + 4);
          float xf = __shfl(acc[e], gsrc + 8);
          float xo = __shfl(acc[e], gsrc + 12);
          float cn = cv[e] * fsigm(xf) + ftanh(xg) * fsigm(xi);
          cv[e] = cn;
          float hv = ftanh(cn) * fsigm(xo);
          if (e == 0) hh0 = hv;
          else if (e == 1) hh1 = hv;
          else if (e == 2) hh2 = hv;
          else hh3 = hv;
        }
        int rr = l15 >> 2;
        float hexp = rr == 0 ? hh0 : rr == 1 ? hh1 : rr == 2 ? hh2 : hh3;
        float p0 = __shfl(hexp, psrc + 0);
        float p1s = __shfl(hexp, psrc + 1);
        float p2s = __shfl(hexp, psrc + 2);
        float p3s = __shfl(hexp, psrc + 3);
        if (lane < 16) {
          u64 pk = (u64)(unsigned short)f2bf(p0) | ((u64)(unsigned short)f2bf(p1s) << 16) |
                   ((u64)(unsigned short)f2bf(p2s) << 32) |
                   ((u64)(unsigned short)f2bf(p3s) << 48);
          int oidx = (group * 16 + lane) * 256 + nsl * 4 + wv;
          if (r < 256)
            __hip_atomic_store(h2ex + (r & 1) * 16384 + oidx, pk, __ATOMIC_RELAXED,
                               __HIP_MEMORY_SCOPE_AGENT);
          else
            hTy[oidx] = pk;  // h2(255) = hT_y
        }
      }
    }

    if (r < 256) {
      asm volatile("s_waitcnt vmcnt(0)" ::: "memory");
      __syncthreads();
      if (tid == 0)
        __hip_atomic_store(arr + ((group << 6) + nsl) * 32, (unsigned)(r + 1),
                           __ATOMIC_RELAXED, __HIP_MEMORY_SCOPE_AGENT);
    }
    gcur = gnext;
  }
}

// ---- final projection, split-K=2 --------------------------------------------
__global__ __launch_bounds__(256) void k_final(const short* __restrict__ hT,
                                               const float* __restrict__ W3,
                                               float* __restrict__ partial) {
  __shared__ float hst[64][64];
  int tid = threadIdx.x;
  int n = blockIdx.x * 256 + tid;
  int kbase = blockIdx.y * 512;
  float acc[64];
#pragma unroll
  for (int i = 0; i < 64; ++i) acc[i] = 0.f;
  int bb = tid >> 2, part = tid & 3;
  for (int kc = 0; kc < 512; kc += 64) {
    __syncthreads();
    s16x8 v0 = *(const s16x8*)(hT + bb * HID + kbase + kc + part * 16);
    s16x8 v1 = *(const s16x8*)(hT + bb * HID + kbase + kc + part * 16 + 8);
#pragma unroll
    for (int e = 0; e < 8; ++e) {
      hst[part * 16 + e][bb] = bf2f(v0[e]);
      hst[part * 16 + 8 + e][bb] = bf2f(v1[e]);
    }
    __syncthreads();
    for (int k = 0; k < 64; ++k) {
      float wv = W3[(size_t)(kbase + kc + k) * N_CLASS + n];
      const float4* hp = (const float4*)&hst[k][0];
#pragma unroll
      for (int b4 = 0; b4 < 16; ++b4) {
        float4 h4 = hp[b4];
        acc[b4 * 4 + 0] += h4.x * wv;
        acc[b4 * 4 + 1] += h4.y * wv;
        acc[b4 * 4 + 2] += h4.z * wv;
        acc[b4 * 4 + 3] += h4.w * wv;
      }
    }
  }
#pragma unroll
  for (int b = 0; b < 64; ++b)
    partial[((size_t)blockIdx.y * 64 + b) * N_CLASS + n] = acc[b];
}

__global__ void k_fincomb(const float* __restrict__ partial, const float* __restrict__ b2,
                          float* __restrict__ out) {
  int n = blockIdx.x * 256 + threadIdx.x;
  int b = blockIdx.y;
  out[(size_t)b * N_CLASS + n] =
      partial[(size_t)b * N_CLASS + n] + partial[((size_t)64 + b) * N_CLASS + n] + b2[n];
}

extern "C" void kernel_launch(void* const* d_in, const int* in_sizes, int n_in, void* d_out,
                              int out_size, void* d_ws, size_t ws_size, hipStream_t stream) {
  (void)in_sizes; (void)n_in; (void)out_size; (void)ws_size;
  const int* X = (const int*)d_in[0];
  const float* C = (const float*)d_in[1];
  const float* W1 = (const float*)d_in[2];
  const float* W_xi = (const float*)d_in[3];
  const float* W_xf = (const float*)d_in[4];
  const float* W_xo = (const float*)d_in[5];
  const float* W2 = (const float*)d_in[6];
  const float* W_hi = (const float*)d_in[7];
  const float* W_hf = (const float*)d_in[8];
  const float* W_ho = (const float*)d_in[9];
  const float* b1 = (const float*)d_in[10];
  const float* b_i = (const float*)d_in[11];
  const float* b_f = (const float*)d_in[12];
  const float* b_o = (const float*)d_in[13];
  const float* W1_y = (const float*)d_in[14];
  const float* W_xi_y = (const float*)d_in[15];
  const float* W_xf_y = (const float*)d_in[16];
  const float* W_xo_y = (const float*)d_in[17];
  const float* W2_y = (const float*)d_in[18];
  const float* W_hi_y = (const float*)d_in[19];
  const float* W_hf_y = (const float*)d_in[20];
  const float* W_ho_y = (const float*)d_in[21];
  const float* b1_y = (const float*)d_in[22];
  const float* b_i_y = (const float*)d_in[23];
  const float* b_f_y = (const float*)d_in[24];
  const float* b_o_y = (const float*)d_in[25];
  const float* W3 = (const float*)d_in[26];
  const float* b2 = (const float*)d_in[27];
  const float* h0 = (const float*)d_in[28];
  const float* c0 = (const float*)d_in[29];
  const float* h0_y = (const float*)d_in[30];
  const float* c0_y = (const float*)d_in[31];

  char* w = (char*)d_ws;
  size_t off = 0;
  auto take = [&](size_t bytes) {
    char* p = w + off;
    off += (bytes + 255) & ~(size_t)255;
    return p;
  };
  short* wx1 = (short*)take(64UL * NG4 * 8 * 2);
  short* wh1 = (short*)take(128UL * NG4 * 8 * 2);
  short* wx2 = (short*)take(128UL * NG4 * 8 * 2);
  short* wh2 = (short*)take(128UL * NG4 * 8 * 2);
  short* xs = (short*)take((size_t)SEQ * BATCH * EMB * 2);
  u64* G1sw = (u64*)take((size_t)SEQ * 65536 * 8);  // 134MB; partials alias later
  float* bc1 = (float*)take(NG4 * 4);
  float* bc2 = (float*)take(NG4 * 4);
  u64* h1ex = (u64*)take(2UL * 16384 * 8);
  u64* h2ex = (u64*)take(2UL * 16384 * 8);
  u64* hTy = (u64*)take(16384UL * 8);
  unsigned* flags = (unsigned*)take(65536);

  hipMemsetAsync(flags, 0, 65536, stream);
  k_bcat<<<16, 256, 0, stream>>>(b1, b_i, b_f, b_o, bc1);
  k_bcat<<<16, 256, 0, stream>>>(b1_y, b_i_y, b_f_y, b_o_y, bc2);
  k_f2bf<<<256, 256, 0, stream>>>(h0, (short*)h1ex + 65536, BATCH * HID);
  k_f2bf<<<256, 256, 0, stream>>>(h0_y, (short*)h2ex, BATCH * HID);
  k_conv_w4<<<dim3(256, 1, 4), 256, 0, stream>>>(W1, W_xi, W_xf, W_xo, wx1, 512);
  k_conv_w4<<<dim3(512, 1, 4), 256, 0, stream>>>(W2, W_hi, W_hf, W_ho, wh1, 1024);
  k_conv_w4<<<dim3(512, 1, 4), 256, 0, stream>>>(W1_y, W_xi_y, W_xf_y, W_xo_y, wx2, 1024);
  k_conv_w4<<<dim3(512, 1, 4), 256, 0, stream>>>(W2_y, W_hi_y, W_hf_y, W_ho_y, wh2, 1024);
  k_embed<<<SEQ * BATCH, 256, 0, stream>>>(X, C, xs);
  k_mega<<<512, 512, 0, stream>>>(G1sw, wh1, wx2, wh2, bc2, h1ex, h2ex, c0, c0_y, hTy,
                                  flags, xs, wx1, bc1);
  float* partial = (float*)G1sw;
  k_final<<<dim3(125, 2), 256, 0, stream>>>((const short*)hTy, W3, partial);
  k_fincomb<<<dim3(125, 64), 256, 0, stream>>>(partial, b2, (float*)d_out);
}

// Round 13
// 2241.598 us; speedup vs baseline: 2.3035x; 2.3035x over previous
//
#include <hip/hip_runtime.h>
#include <hip/hip_bf16.h>

// TextRNN: embed -> 2-layer LSTM (B=64,T=256,H=1024) -> proj 32000, f32 out.
// R13 = R10 k_mega (best verified: ~1828us, 7.1us/round sync-protocol floor)
// + safe tail consolidation: fused bias/seed prep (1 launch), grid-stride
// embed, k_final split-K=4. Weight conversion stays as 4 k_conv_w4 launches
// (R12's device pointer tables needed H2D memcpyAsync from host stack ->
// graph-capture abort). k_mega untouched.

typedef __attribute__((ext_vector_type(8))) short s16x8;
typedef __attribute__((ext_vector_type(4))) float f32x4;
typedef unsigned long long u64;

#define N_CLASS 32000
#define EMB 512
#define HID 1024
#define BATCH 64
#define SEQ 256
#define NG4 4096

#define PIN(v) asm volatile("" : "+v"(v))

static __device__ __forceinline__ short f2bf(float x) {
  __hip_bfloat16 h = __float2bfloat16(x);
  return *reinterpret_cast<short*>(&h);
}
static __device__ __forceinline__ float bf2f(short x) {
  __hip_bfloat16 h = *reinterpret_cast<__hip_bfloat16*>(&x);
  return __bfloat162float(h);
}
static __device__ __forceinline__ float fsigm(float x) {
  return __builtin_amdgcn_rcpf(1.f + __expf(-x));
}
static __device__ __forceinline__ float ftanh(float x) {
  return 2.f * __builtin_amdgcn_rcpf(1.f + __expf(-2.f * x)) - 1.f;
}

// ---- weight conversion to swizzled bf16 B-layout: sw[((k>>3)*4096+n)*8+(k&7)]
__global__ void k_conv_w4(const float* __restrict__ Wg, const float* __restrict__ Wi,
                          const float* __restrict__ Wf, const float* __restrict__ Wo,
                          short* __restrict__ sw, int K) {
  int i = blockIdx.x * 256 + threadIdx.x;
  int k8 = i >> 10, j = i & 1023;
  if (k8 >= (K >> 3)) return;
  const float* W = blockIdx.z == 0 ? Wg : blockIdx.z == 1 ? Wi : blockIdx.z == 2 ? Wf : Wo;
  s16x8 v;
#pragma unroll
  for (int e = 0; e < 8; ++e) v[e] = f2bf(W[(size_t)(k8 * 8 + e) * 1024 + j]);
  *(s16x8*)(sw + ((size_t)k8 * NG4 + blockIdx.z * 1024 + j) * 8) = v;
}

// ---- fused bias-cat + h-seed prep: one launch --------------------------------
__global__ void k_prep_misc(const float* __restrict__ b1, const float* __restrict__ b_i,
                            const float* __restrict__ b_f, const float* __restrict__ b_o,
                            const float* __restrict__ b1y, const float* __restrict__ b_iy,
                            const float* __restrict__ b_fy, const float* __restrict__ b_oy,
                            const float* __restrict__ h0, const float* __restrict__ h0y,
                            float* __restrict__ bc1, float* __restrict__ bc2,
                            short* __restrict__ h1seed, short* __restrict__ h2seed) {
  int i = blockIdx.x * 256 + threadIdx.x;
  if (i < 4096) {
    const float* s = (i >> 10) == 0 ? b1 : (i >> 10) == 1 ? b_i : (i >> 10) == 2 ? b_f : b_o;
    bc1[i] = s[i & 1023];
    const float* sy =
        (i >> 10) == 0 ? b1y : (i >> 10) == 1 ? b_iy : (i >> 10) == 2 ? b_fy : b_oy;
    bc2[i] = sy[i & 1023];
  }
  int j = i - 4096;
  if (j >= 0 && j < BATCH * HID) {
    h1seed[j] = f2bf(h0[j]);
    h2seed[j] = f2bf(h0y[j]);
  }
}

// ---- embedding gather, grid-stride ------------------------------------------
__global__ void k_embed(const int* __restrict__ X, const float* __restrict__ C,
                        short* __restrict__ xs) {
  for (int r = blockIdx.x; r < SEQ * BATCH; r += gridDim.x) {
    int t = r >> 6, b = r & 63;
    int idx = X[b * SEQ + t];
    const float* src = C + (size_t)idx * EMB;
    float2 v = *(const float2*)(src + threadIdx.x * 2);
    short* dst = xs + (size_t)r * EMB + threadIdx.x * 2;
    dst[0] = f2bf(v.x);
    dst[1] = f2bf(v.y);
  }
}

// ---- G1 pre-GEMM: Gsw (bf16 packed u64) = xs@Wx1 + b1 ------------------------
__global__ __launch_bounds__(256) void k_gemx(const short* __restrict__ A,
                                              const short* __restrict__ Bsw,
                                              const float* __restrict__ bias,
                                              u64* __restrict__ Gsw) {
  __shared__ short lds[4096 * 8];  // 64KB B panel (K=512 x BN=64)
  int tid = threadIdx.x;
  int n0 = blockIdx.x * 64;
  for (int cid = tid; cid < 4096; cid += 256) {
    int k8 = cid >> 6, nl = cid & 63;
    *(s16x8*)(lds + (size_t)cid * 8) = *(const s16x8*)(Bsw + ((size_t)k8 * NG4 + n0 + nl) * 8);
  }
  __syncthreads();
  int lane = tid & 63, wid = tid >> 6;
  int l15 = lane & 15, l4 = lane >> 4;
  int ms = wid >> 1, ns = wid & 1;
  for (int m0 = blockIdx.y * 64; m0 < SEQ * BATCH; m0 += gridDim.y * 64) {
    f32x4 acc[2][2];
#pragma unroll
    for (int i = 0; i < 2; ++i)
#pragma unroll
      for (int j = 0; j < 2; ++j) acc[i][j] = (f32x4){0.f, 0.f, 0.f, 0.f};
    const short* a0p = A + (size_t)(m0 + ms * 32 + l15) * EMB + l4 * 8;
    const short* a1p = a0p + (size_t)16 * EMB;
#pragma unroll 4
    for (int kc = 0; kc < 16; ++kc) {
      s16x8 av0 = *(const s16x8*)(a0p + kc * 32);
      s16x8 av1 = *(const s16x8*)(a1p + kc * 32);
#pragma unroll
      for (int j = 0; j < 2; ++j) {
        s16x8 bv = *(const s16x8*)(lds + (size_t)((kc * 4 + l4) * 64 + ns * 32 + j * 16 + l15) * 8);
        acc[0][j] = __builtin_amdgcn_mfma_f32_16x16x32_bf16(av0, bv, acc[0][j], 0, 0, 0);
        acc[1][j] = __builtin_amdgcn_mfma_f32_16x16x32_bf16(av1, bv, acc[1][j], 0, 0, 0);
      }
    }
    int t = m0 >> 6;
#pragma unroll
    for (int i = 0; i < 2; ++i)
#pragma unroll
      for (int j = 0; j < 2; ++j) {
        int grp = ms * 2 + i;
        int colg = n0 + ns * 32 + j * 16 + l15;
        float bv = bias[colg];
        int q = colg >> 10, nslc = (colg >> 4) & 63;
        u64 pk = 0;
#pragma unroll
        for (int e = 0; e < 4; ++e)
          pk |= (u64)(unsigned short)f2bf(acc[i][j][e] + bv) << (16 * e);
        size_t slot = ((((size_t)t * 4 + grp) * 64 + nslc) * 4 + q) * 64 + l4 * 16 + l15;
        Gsw[slot] = pk;
      }
  }
}

// ---- persistent 2-layer recurrence, split-K wave pairs (R10 verbatim) --------
__global__ __launch_bounds__(512, 2) void k_mega(
    const u64* __restrict__ G64, const short* __restrict__ Wh1sw,
    const short* __restrict__ Wx2sw, const short* __restrict__ Wh2sw,
    const float* __restrict__ bc2, u64* __restrict__ h1ex, u64* __restrict__ h2ex,
    const float* __restrict__ c0, const float* __restrict__ c0y,
    u64* __restrict__ hTy, unsigned* __restrict__ flags) {
  __shared__ short a_lds[2 * 16 * 1024];  // 64KB: A1 | A2, XOR-swizzled rows
  __shared__ f32x4 xch[8][64];            // 8KB partial-sum exchange
  const int tid = threadIdx.x;
  const int lane = tid & 63, W = tid >> 6;
  const int wv = W & 3, khalf = W >> 2;
  const int l15 = lane & 15, l4 = lane >> 4;
  // nsl-colocating XCD remap: all 4 group-copies of a weight slice on one XCD.
  const int xcd = (int)blockIdx.x & 7;
  const int idx = (int)blockIdx.x >> 3;        // 0..31
  const int group = idx & 3;
  const int nsl = ((idx >> 2) << 3) | xcd;     // 8*(idx>>2) + xcd
  const int col = (l15 >> 2) * 1024 + nsl * 16 + wv * 4 + (l15 & 3);

  s16x8 b1r[16], bxr[16], b2r[16];
#pragma unroll
  for (int j = 0; j < 16; ++j) {
    size_t o = ((size_t)((khalf * 16 + j) * 4 + l4) * NG4 + col) * 8;
    b1r[j] = *(const s16x8*)(Wh1sw + o);
    PIN(b1r[j]);
  }
#pragma unroll
  for (int j = 0; j < 16; ++j) {
    size_t o = ((size_t)((khalf * 16 + j) * 4 + l4) * NG4 + col) * 8;
    bxr[j] = *(const s16x8*)(Wx2sw + o);
    PIN(bxr[j]);
  }
#pragma unroll
  for (int j = 0; j < 16; ++j) {
    size_t o = ((size_t)((khalf * 16 + j) * 4 + l4) * NG4 + col) * 8;
    b2r[j] = *(const s16x8*)(Wh2sw + o);
    PIN(b2r[j]);
  }
  const float bias2 = bc2[col];
  float cv[4];  // c1 on waves 0-3, c2 on waves 4-7
#pragma unroll
  for (int e = 0; e < 4; ++e) {
    int gi = (group * 16 + l4 * 4 + e) * HID + nsl * 16 + wv * 4 + (l15 & 3);
    cv[e] = (W < 4 ? c0 : c0y)[gi];
  }
  unsigned* arr = flags;  // [4][64] slots, stride 32 u32 (128B)
  const int srow = tid >> 5, sc5 = tid & 31;
  const int exrow = (group * 16 + srow) * 256;
  const size_t gbase =
      (((size_t)group * 64 + nsl) * 4 + (l15 >> 2)) * 64 + l4 * 16 + wv * 4 + (l15 & 3);
  u64 gcur = (W < 4) ? G64[gbase] : 0;
  u64 gnext = 0;
  const int gsrc = l4 * 16 + (l15 & 3);
  const int psrc = ((l15 >> 2) << 4) + ((l15 & 3) << 2);
  const int swzm = (l15 & 7) << 4;
  const int abase = l15 * 2048 + khalf * 1024 + l4 * 16;

  for (int r = 0; r <= 256; ++r) {
    if (W < 4 && r + 1 < 256) gnext = G64[gbase + (size_t)(r + 1) * 65536];
    if (r > 0) {
      if (tid < 64) {
        unsigned* p = arr + ((group << 6) + tid) * 32;
        while (__hip_atomic_load(p, __ATOMIC_RELAXED, __HIP_MEMORY_SCOPE_AGENT) <
               (unsigned)r)
          __builtin_amdgcn_s_sleep(1);
      }
      __syncthreads();
      asm volatile("" ::: "memory");
    }
    {  // stage A1 = h1(r-1), A2 = h2(r-2) from ring slot (r+1)&1
      const int slot = (r + 1) & 1;
      const u64* s1 = h1ex + slot * 16384 + exrow;
      const u64* s2 = h2ex + slot * 16384 + exrow;
#pragma unroll
      for (int i = 0; i < 8; ++i) {
        int chunk = sc5 + (i << 5);
        u64 v1 = __hip_atomic_load(s1 + chunk, __ATOMIC_RELAXED, __HIP_MEMORY_SCOPE_AGENT);
        u64 v2 = __hip_atomic_load(s2 + chunk, __ATOMIC_RELAXED, __HIP_MEMORY_SCOPE_AGENT);
        int bo = (srow * 2048 + chunk * 8) ^ ((srow & 7) << 4);
        *(u64*)((char*)a_lds + bo) = v1;
        *(u64*)((char*)a_lds + 32768 + bo) = v2;
      }
    }
    __syncthreads();

    f32x4 p1, p2a, p2b;
    if (W < 4) {
#pragma unroll
      for (int e = 0; e < 4; ++e)
        p1[e] = __uint_as_float((unsigned)((gcur >> (16 * e)) & 0xffffu) << 16);
      p2a = (f32x4){0.f, 0.f, 0.f, 0.f};
    } else {
      p1 = (f32x4){0.f, 0.f, 0.f, 0.f};
      p2a = (f32x4){bias2, bias2, bias2, bias2};
    }
    p2b = (f32x4){0.f, 0.f, 0.f, 0.f};
#pragma unroll
    for (int j = 0; j < 16; ++j) {
      int o = (abase + j * 64) ^ swzm;
      s16x8 a1 = *(const s16x8*)((const char*)a_lds + o);
      s16x8 a2 = *(const s16x8*)((const char*)a_lds + 32768 + o);
      p1 = __builtin_amdgcn_mfma_f32_16x16x32_bf16(a1, b1r[j], p1, 0, 0, 0);
      p2a = __builtin_amdgcn_mfma_f32_16x16x32_bf16(a1, bxr[j], p2a, 0, 0, 0);
      p2b = __builtin_amdgcn_mfma_f32_16x16x32_bf16(a2, b2r[j], p2b, 0, 0, 0);
    }
    f32x4 p2 = p2a + p2b;
    if (W < 4) {
      if (r >= 1) xch[W][lane] = p2;
    } else {
      if (r < 256) xch[W][lane] = p1;
    }
    __syncthreads();

    if (W < 4) {
      if (r < 256) {  // layer-1 activation, h1(r)
        f32x4 po = xch[W + 4][lane];
        f32x4 acc = p1 + po;
        float hh0, hh1, hh2, hh3;
#pragma unroll
        for (int e = 0; e < 4; ++e) {
          float xg = __shfl(acc[e], gsrc + 0);
          float xi = __shfl(acc[e], gsrc + 4);
          float xf = __shfl(acc[e], gsrc + 8);
          float xo = __shfl(acc[e], gsrc + 12);
          float cn = cv[e] * fsigm(xf) + ftanh(xg) * fsigm(xi);
          cv[e] = cn;
          float hv = ftanh(cn) * fsigm(xo);
          if (e == 0) hh0 = hv;
          else if (e == 1) hh1 = hv;
          else if (e == 2) hh2 = hv;
          else hh3 = hv;
        }
        int rr = l15 >> 2;
        float hexp = rr == 0 ? hh0 : rr == 1 ? hh1 : rr == 2 ? hh2 : hh3;
        float p0 = __shfl(hexp, psrc + 0);
        float p1s = __shfl(hexp, psrc + 1);
        float p2s = __shfl(hexp, psrc + 2);
        float p3s = __shfl(hexp, psrc + 3);
        if (lane < 16) {
          u64 pk = (u64)(unsigned short)f2bf(p0) | ((u64)(unsigned short)f2bf(p1s) << 16) |
                   ((u64)(unsigned short)f2bf(p2s) << 32) |
                   ((u64)(unsigned short)f2bf(p3s) << 48);
          __hip_atomic_store(
              h1ex + (r & 1) * 16384 + (group * 16 + lane) * 256 + nsl * 4 + wv, pk,
              __ATOMIC_RELAXED, __HIP_MEMORY_SCOPE_AGENT);
        }
      }
    } else {
      if (r >= 1) {  // layer-2 activation, h2(r-1)
        f32x4 po = xch[W - 4][lane];
        f32x4 acc = p2 + po;
        float hh0, hh1, hh2, hh3;
#pragma unroll
        for (int e = 0; e < 4; ++e) {
          float xg = __shfl(acc[e], gsrc + 0);
          float xi = __shfl(acc[e], gsrc + 4);
          float xf = __shfl(acc[e], gsrc + 8);
          float xo = __shfl(acc[e], gsrc + 12);
          float cn = cv[e] * fsigm(xf) + ftanh(xg) * fsigm(xi);
          cv[e] = cn;
          float hv = ftanh(cn) * fsigm(xo);
          if (e == 0) hh0 = hv;
          else if (e == 1) hh1 = hv;
          else if (e == 2) hh2 = hv;
          else hh3 = hv;
        }
        int rr = l15 >> 2;
        float hexp = rr == 0 ? hh0 : rr == 1 ? hh1 : rr == 2 ? hh2 : hh3;
        float p0 = __shfl(hexp, psrc + 0);
        float p1s = __shfl(hexp, psrc + 1);
        float p2s = __shfl(hexp, psrc + 2);
        float p3s = __shfl(hexp, psrc + 3);
        if (lane < 16) {
          u64 pk = (u64)(unsigned short)f2bf(p0) | ((u64)(unsigned short)f2bf(p1s) << 16) |
                   ((u64)(unsigned short)f2bf(p2s) << 32) |
                   ((u64)(unsigned short)f2bf(p3s) << 48);
          int idx2 = (group * 16 + lane) * 256 + nsl * 4 + wv;
          if (r < 256)
            __hip_atomic_store(h2ex + (r & 1) * 16384 + idx2, pk, __ATOMIC_RELAXED,
                               __HIP_MEMORY_SCOPE_AGENT);
          else
            hTy[idx2] = pk;  // h2(255) = hT_y
        }
      }
    }

    if (r < 256) {
      asm volatile("s_waitcnt vmcnt(0)" ::: "memory");
      __syncthreads();
      if (tid == 0)
        __hip_atomic_store(arr + ((group << 6) + nsl) * 32, (unsigned)(r + 1),
                           __ATOMIC_RELAXED, __HIP_MEMORY_SCOPE_AGENT);
    }
    gcur = gnext;
  }
}

// ---- final projection, split-K=4 --------------------------------------------
__global__ __launch_bounds__(256) void k_final(const short* __restrict__ hT,
                                               const float* __restrict__ W3,
                                               float* __restrict__ partial) {
  __shared__ float hst[64][64];
  int tid = threadIdx.x;
  int n = blockIdx.x * 256 + tid;
  int kbase = blockIdx.y * 256;
  float acc[64];
#pragma unroll
  for (int i = 0; i < 64; ++i) acc[i] = 0.f;
  int bb = tid >> 2, part = tid & 3;
  for (int kc = 0; kc < 256; kc += 64) {
    __syncthreads();
    s16x8 v0 = *(const s16x8*)(hT + bb * HID + kbase + kc + part * 16);
    s16x8 v1 = *(const s16x8*)(hT + bb * HID + kbase + kc + part * 16 + 8);
#pragma unroll
    for (int e = 0; e < 8; ++e) {
      hst[part * 16 + e][bb] = bf2f(v0[e]);
      hst[part * 16 + 8 + e][bb] = bf2f(v1[e]);
    }
    __syncthreads();
    for (int k = 0; k < 64; ++k) {
      float wv = W3[(size_t)(kbase + kc + k) * N_CLASS + n];
      const float4* hp = (const float4*)&hst[k][0];
#pragma unroll
      for (int b4 = 0; b4 < 16; ++b4) {
        float4 h4 = hp[b4];
        acc[b4 * 4 + 0] += h4.x * wv;
        acc[b4 * 4 + 1] += h4.y * wv;
        acc[b4 * 4 + 2] += h4.z * wv;
        acc[b4 * 4 + 3] += h4.w * wv;
      }
    }
  }
#pragma unroll
  for (int b = 0; b < 64; ++b)
    partial[((size_t)blockIdx.y * 64 + b) * N_CLASS + n] = acc[b];
}

__global__ void k_fincomb(const float* __restrict__ partial, const float* __restrict__ b2,
                          float* __restrict__ out) {
  int n = blockIdx.x * 256 + threadIdx.x;
  int b = blockIdx.y;
  out[(size_t)b * N_CLASS + n] = partial[(size_t)b * N_CLASS + n] +
                                 partial[((size_t)64 + b) * N_CLASS + n] +
                                 partial[((size_t)128 + b) * N_CLASS + n] +
                                 partial[((size_t)192 + b) * N_CLASS + n] + b2[n];
}

extern "C" void kernel_launch(void* const* d_in, const int* in_sizes, int n_in, void* d_out,
                              int out_size, void* d_ws, size_t ws_size, hipStream_t stream) {
  (void)in_sizes; (void)n_in; (void)out_size; (void)ws_size;
  const int* X = (const int*)d_in[0];
  const float* C = (const float*)d_in[1];
  const float* W1 = (const float*)d_in[2];
  const float* W_xi = (const float*)d_in[3];
  const float* W_xf = (const float*)d_in[4];
  const float* W_xo = (const float*)d_in[5];
  const float* W2 = (const float*)d_in[6];
  const float* W_hi = (const float*)d_in[7];
  const float* W_hf = (const float*)d_in[8];
  const float* W_ho = (const float*)d_in[9];
  const float* b1 = (const float*)d_in[10];
  const float* b_i = (const float*)d_in[11];
  const float* b_f = (const float*)d_in[12];
  const float* b_o = (const float*)d_in[13];
  const float* W1_y = (const float*)d_in[14];
  const float* W_xi_y = (const float*)d_in[15];
  const float* W_xf_y = (const float*)d_in[16];
  const float* W_xo_y = (const float*)d_in[17];
  const float* W2_y = (const float*)d_in[18];
  const float* W_hi_y = (const float*)d_in[19];
  const float* W_hf_y = (const float*)d_in[20];
  const float* W_ho_y = (const float*)d_in[21];
  const float* b1_y = (const float*)d_in[22];
  const float* b_i_y = (const float*)d_in[23];
  const float* b_f_y = (const float*)d_in[24];
  const float* b_o_y = (const float*)d_in[25];
  const float* W3 = (const float*)d_in[26];
  const float* b2 = (const float*)d_in[27];
  const float* h0 = (const float*)d_in[28];
  const float* c0 = (const float*)d_in[29];
  const float* h0_y = (const float*)d_in[30];
  const float* c0_y = (const float*)d_in[31];

  char* w = (char*)d_ws;
  size_t off = 0;
  auto take = [&](size_t bytes) {
    char* p = w + off;
    off += (bytes + 255) & ~(size_t)255;
    return p;
  };
  short* wx1 = (short*)take(64UL * NG4 * 8 * 2);
  short* wh1 = (short*)take(128UL * NG4 * 8 * 2);
  short* wx2 = (short*)take(128UL * NG4 * 8 * 2);
  short* wh2 = (short*)take(128UL * NG4 * 8 * 2);
  short* xs = (short*)take((size_t)SEQ * BATCH * EMB * 2);
  u64* G1sw = (u64*)take((size_t)SEQ * 65536 * 8);  // 134MB; partials alias later
  float* bc1 = (float*)take(NG4 * 4);
  float* bc2 = (float*)take(NG4 * 4);
  u64* h1ex = (u64*)take(2UL * 16384 * 8);
  u64* h2ex = (u64*)take(2UL * 16384 * 8);
  u64* hTy = (u64*)take(16384UL * 8);
  unsigned* flags = (unsigned*)take(65536);

  hipMemsetAsync(flags, 0, 65536, stream);
  // seeds: h1ex slot1 <- h0 (read at r=0), h2ex slot0 <- h0_y (read at r=1)
  k_prep_misc<<<288, 256, 0, stream>>>(b1, b_i, b_f, b_o, b1_y, b_i_y, b_f_y, b_o_y, h0,
                                       h0_y, bc1, bc2, (short*)h1ex + 65536, (short*)h2ex);
  k_conv_w4<<<dim3(256, 1, 4), 256, 0, stream>>>(W1, W_xi, W_xf, W_xo, wx1, 512);
  k_conv_w4<<<dim3(512, 1, 4), 256, 0, stream>>>(W2, W_hi, W_hf, W_ho, wh1, 1024);
  k_conv_w4<<<dim3(512, 1, 4), 256, 0, stream>>>(W1_y, W_xi_y, W_xf_y, W_xo_y, wx2, 1024);
  k_conv_w4<<<dim3(512, 1, 4), 256, 0, stream>>>(W2_y, W_hi_y, W_hf_y, W_ho_y, wh2, 1024);
  k_embed<<<2048, 256, 0, stream>>>(X, C, xs);
  k_gemx<<<dim3(64, 16), 256, 0, stream>>>(xs, wx1, bc1, G1sw);
  k_mega<<<256, 512, 0, stream>>>(G1sw, wh1, wx2, wh2, bc2, h1ex, h2ex, c0, c0_y, hTy,
                                  flags);
  float* partial = (float*)G1sw;
  k_final<<<dim3(125, 4), 256, 0, stream>>>((const short*)hTy, W3, partial);
  k_fincomb<<<dim3(125, 64), 256, 0, stream>>>(partial, b2, (float*)d_out);
}